// Round 3
// baseline (224.901 us; speedup 1.0000x reference)
//
#include <hip/hip_runtime.h>
#include <stdint.h>

typedef __bf16 bf16_t;
typedef __bf16 bf16x8 __attribute__((ext_vector_type(8)));
typedef __bf16 bf16x4 __attribute__((ext_vector_type(4)));
typedef float  f32x4  __attribute__((ext_vector_type(4)));

// ---------- helpers ----------

__device__ __forceinline__ void gload16(const void* g, void* lds)
{
    __builtin_amdgcn_global_load_lds(
        (__attribute__((address_space(1))) void*)(void*)g,
        (__attribute__((address_space(3))) void*)lds,
        16, 0, 0);
}

// NOTE: operands SWAPPED at call sites (mfma(b,a,acc)) so the C/D fragment
// holds 4 CONSECUTIVE COLUMNS per lane: C[row=lane&15][col=(lane>>4)*4+r].
__device__ __forceinline__ f32x4 mfma16(bf16x8 a, bf16x8 b, f32x4 c)
{
    return __builtin_amdgcn_mfma_f32_16x16x32_bf16(a, b, c, 0, 0, 0);
}

#define SBAR()   asm volatile("s_barrier" ::: "memory")
#define LGKM0()  asm volatile("s_waitcnt lgkmcnt(0)" ::: "memory")
#define VMCNT(N) asm volatile("s_waitcnt vmcnt(" #N ")" ::: "memory")

// ---------- prep kernels ----------

__global__ __launch_bounds__(256)
void cast_f32_bf16(const float* __restrict__ in, bf16_t* __restrict__ out, int n4)
{
    const int i = blockIdx.x * blockDim.x + threadIdx.x;
    if (i >= n4) return;
    float4 f = *(const float4*)&in[(size_t)i * 4];
    bf16x4 o;
    o[0] = (bf16_t)f.x; o[1] = (bf16_t)f.y; o[2] = (bf16_t)f.z; o[3] = (bf16_t)f.w;
    *(bf16x4*)&out[(size_t)i * 4] = o;
}

__global__ __launch_bounds__(256)
void gather_cast_x(const float* __restrict__ x, bf16_t* __restrict__ Xe)
{
    const int m = blockIdx.x;
    const int b = m >> 11, g = (m >> 8) & 7, j = m & 255;
    const float* src = x + ((size_t)b * 4096 + g * 512 + 2 * j) * 1024;
    bf16_t* dst = Xe + (size_t)m * 1024;
    const int t = threadIdx.x;
    float4 f = *(const float4*)&src[t * 4];
    bf16x4 o;
    o[0] = (bf16_t)f.x; o[1] = (bf16_t)f.y; o[2] = (bf16_t)f.z; o[3] = (bf16_t)f.w;
    *(bf16x4*)&dst[t * 4] = o;
}

// ---------- 256x256 8-phase GEMM: C[M,N] = A[M,K] * B[N,K]^T ----------
// 512 threads = 8 waves (2M x 4N). BK=64. LDS 128KB double-buffered.
// LDS swizzle (NEW): 16B-granule bits (0,1,2) ^= granule bits (3,4,5)
// i.e. byte bits (4,5,6) ^= byte bits (7,8,9) = fr0,fr1,fr2 -> every
// consecutive-8/16/32-lane group of a ds_read_b128 hits distinct bank quads.
template<int EPI>   // 0 = store bf16
__global__ __launch_bounds__(512, 2)
void gemm256(const bf16_t* __restrict__ A, const bf16_t* __restrict__ B,
             void* __restrict__ Cv, int K, int lda, int ldb, int ldc)
{
    __shared__ __align__(16) char lds[131072];

    const int tid = threadIdx.x;
    const int w = tid >> 6, lane = tid & 63;
    const int wr = w >> 2, wc = w & 3;
    const int fr = lane & 15, fg = lane >> 4;
    const int bn = blockIdx.x, bm = blockIdx.y;
    const int NT = K >> 6;

    // stage-side: pre-swizzled global source granule (involution on bits 0-2 ^= 3-5)
    const int d0 = tid, d1 = 512 + tid;
    const int s0 = d0 ^ ((d0 >> 3) & 7);
    const int s1 = d1 ^ ((d1 >> 3) & 7);
    const size_t fixA0 = ((size_t)(bm * 256 + (s0 >> 9) * 128 + ((s0 >> 3) & 63)) * lda + (s0 & 7) * 8) * 2;
    const size_t fixA1 = ((size_t)(bm * 256 + (s1 >> 9) * 128 + ((s1 >> 3) & 63)) * lda + (s1 & 7) * 8) * 2;
    const size_t fixB0 = ((size_t)(bn * 256 + (s0 >> 8) * 64 + ((s0 >> 3) & 31)) * ldb + (s0 & 7) * 8) * 2;
    const size_t fixB1 = ((size_t)(bn * 256 + (s1 >> 8) * 64 + ((s1 >> 3) & 31)) * ldb + (s1 & 7) * 8) * 2;
    const size_t mqStep = (size_t)64 * lda * 2;
    const size_t nqStep = (size_t)32 * ldb * 2;
    const char* Ac = (const char*)A;
    const char* Bc = (const char*)B;
    const int ldsW = w * 1024;

#define STAGE(T, ISB, Q) do {                                                     \
    const int _b = ((T) & 1) * 65536 + (ISB) * 32768 + (Q) * 16384 + ldsW;        \
    const char *_g0, *_g1;                                                        \
    if (ISB) { _g0 = Bc + (Q)*nqStep + fixB0 + (size_t)(T)*128;                   \
               _g1 = Bc + (Q)*nqStep + fixB1 + (size_t)(T)*128; }                 \
    else     { _g0 = Ac + (Q)*mqStep + fixA0 + (size_t)(T)*128;                   \
               _g1 = Ac + (Q)*mqStep + fixA1 + (size_t)(T)*128; }                 \
    gload16(_g0, lds + _b);                                                       \
    gload16(_g1, lds + _b + 8192);                                                \
} while (0)

    // read-side bases; swizzle = thread-constant XOR of byte bits 4-6 with fr0-2
    const int abase = wr * 8192 + fr * 128 + fg * 16;
    const int bbase = wc * 4096 + fr * 128 + fg * 16;
    const int flip  = (fr & 7) << 4;

    bf16x8 a[4][2], b0[2][2], b1[2][2];
    f32x4 acc[8][4] = {};

#define LOAD_A(MQ, CB) do {                                                                 \
    _Pragma("unroll") for (int mi = 0; mi < 4; ++mi)                                        \
    _Pragma("unroll") for (int ks = 0; ks < 2; ++ks)                                        \
        a[mi][ks] = *(const bf16x8*)(lds + (CB) + (MQ)*16384 +                              \
                                     ((abase + mi*2048 + ks*64) ^ flip));                   \
} while (0)

#define LOAD_B(REG, NQ, CB) do {                                                            \
    _Pragma("unroll") for (int ni = 0; ni < 2; ++ni)                                        \
    _Pragma("unroll") for (int ks = 0; ks < 2; ++ks)                                        \
        REG[ni][ks] = *(const bf16x8*)(lds + (CB) + 32768 + (NQ)*16384 +                    \
                                       ((bbase + ni*2048 + ks*64) ^ flip));                 \
} while (0)

#define MFMA_Q(MQ, REG, NQ) do {                                                            \
    _Pragma("unroll") for (int mi = 0; mi < 4; ++mi)                                        \
    _Pragma("unroll") for (int ni = 0; ni < 2; ++ni)                                        \
    _Pragma("unroll") for (int ks = 0; ks < 2; ++ks)                                        \
        acc[(MQ)*4+mi][(NQ)*2+ni] =                                                         \
            mfma16(REG[ni][ks], a[mi][ks], acc[(MQ)*4+mi][(NQ)*2+ni]);                      \
} while (0)

    // prologue: tile0 {A0,B0,B1,A1}, vmcnt(4); tile1 {A0,B0,B1}, vmcnt(6)
    STAGE(0, 0, 0); STAGE(0, 1, 0); STAGE(0, 1, 1); STAGE(0, 0, 1);
    VMCNT(4);
    STAGE(1, 0, 0); STAGE(1, 1, 0); STAGE(1, 1, 1);
    VMCNT(6);
    SBAR();

    for (int t = 0; t < NT - 2; ++t) {
        const int cb = (t & 1) * 65536;
        LOAD_A(0, cb); LOAD_B(b0, 0, cb);
        STAGE(t + 1, 0, 1);
        SBAR(); LGKM0();
        __builtin_amdgcn_s_setprio(1); MFMA_Q(0, b0, 0); __builtin_amdgcn_s_setprio(0);
        SBAR();
        LOAD_B(b1, 1, cb);
        STAGE(t + 2, 0, 0);
        SBAR(); LGKM0();
        __builtin_amdgcn_s_setprio(1); MFMA_Q(0, b1, 1); __builtin_amdgcn_s_setprio(0);
        SBAR();
        LOAD_A(1, cb);
        STAGE(t + 2, 1, 0);
        SBAR(); LGKM0();
        __builtin_amdgcn_s_setprio(1); MFMA_Q(1, b1, 1); __builtin_amdgcn_s_setprio(0);
        SBAR();
        STAGE(t + 2, 1, 1);
        SBAR();
        __builtin_amdgcn_s_setprio(1); MFMA_Q(1, b0, 0); __builtin_amdgcn_s_setprio(0);
        VMCNT(6);
        SBAR();
    }

    STAGE(NT - 1, 0, 1);
    VMCNT(0);
    SBAR();
    for (int t = NT - 2; t < NT; ++t) {
        const int cb = (t & 1) * 65536;
        LOAD_A(0, cb); LOAD_B(b0, 0, cb);
        LGKM0();
        MFMA_Q(0, b0, 0);
        LOAD_B(b1, 1, cb);
        LGKM0();
        MFMA_Q(0, b1, 1);
        LOAD_A(1, cb);
        LGKM0();
        MFMA_Q(1, b1, 1);
        MFMA_Q(1, b0, 0);
    }

#undef STAGE
#undef LOAD_A
#undef LOAD_B
#undef MFMA_Q

    // epilogue (swapped-operand layout): row = ..+fr, cols = ..+fg*4+r (packed)
    const int r0 = bm * 256 + wr * 128 + fr;
    const int c0 = bn * 256 + wc * 64 + fg * 4;
    if constexpr (EPI == 0) {
        bf16_t* C = (bf16_t*)Cv;
#pragma unroll
        for (int mig = 0; mig < 8; ++mig)
#pragma unroll
            for (int nig = 0; nig < 4; ++nig) {
                bf16x4 o;
#pragma unroll
                for (int r = 0; r < 4; ++r) o[r] = (bf16_t)acc[mig][nig][r];
                *(bf16x4*)&C[(size_t)(r0 + mig * 16) * ldc + c0 + nig * 16] = o;
            }
    }
}

// ---------- GEMM: C[M,N] = A[M,K] * B[N,K]^T (128x128 tile, m97 + swizzle) ----------
// LDS swizzle: 16B-granule bits (0,1) ^= bits (3,4) (= byte bits 4,5 ^= 7,8 = fr1,fr2).
// EPI: 0 = store bf16, 1 = store f32, 2 = scatter f32 into d_out even rows + zero odd.
// tri: if nonzero, blocks with bm==0 use K/2 (lower-triangular A, upper half zero).
template<int EPI>
__global__ __launch_bounds__(256)
void gemm_nt(const bf16_t* __restrict__ A, const bf16_t* __restrict__ B,
             void* __restrict__ Cv,
             int K, int lda, int ldb, int ldc,
             long sA, long sB, long sC, int tri)
{
    __shared__ __align__(16) bf16_t Asm[128 * 32];
    __shared__ __align__(16) bf16_t Bsm[128 * 32];

    const int tid  = threadIdx.x;
    const int wave = tid >> 6;
    const int lane = tid & 63;
    const int bn = blockIdx.x, bm = blockIdx.y, bz = blockIdx.z;
    const int wr = wave >> 1, wc = wave & 1;

    const bf16_t* Ab = A + (long)bz * sA;
    const bf16_t* Bb = B + (long)bz * sB;

    const int Keff = (tri && bm == 0) ? (K >> 1) : K;

    // pre-swizzled source decode per stage call (granule bits 0,1 ^= 3,4)
    const int sw0 = tid ^ ((tid >> 3) & 3);
    const int dd1 = tid + 256;
    const int sw1 = dd1 ^ ((dd1 >> 3) & 3);
    const bf16_t* a0 = Ab + (size_t)(bm * 128 + (sw0 >> 2)) * lda + (sw0 & 3) * 8;
    const bf16_t* a1 = Ab + (size_t)(bm * 128 + (sw1 >> 2)) * lda + (sw1 & 3) * 8;
    const bf16_t* b0 = Bb + (size_t)(bn * 128 + (sw0 >> 2)) * ldb + (sw0 & 3) * 8;
    const bf16_t* b1 = Bb + (size_t)(bn * 128 + (sw1 >> 2)) * ldb + (sw1 & 3) * 8;
    char* ldsA = (char*)Asm + wave * 1024;
    char* ldsB = (char*)Bsm + wave * 1024;

    f32x4 acc[4][4] = {};

    const int frow = lane & 15;
    const int fk   = (lane >> 4) * 8;
    const int flip = (frow & 6) << 2;   // element-index XOR (bits 3,4 ^= fr1,fr2)

    for (int k0 = 0; k0 < Keff; k0 += 32) {
        gload16(a0, ldsA);
        gload16(a1, ldsA + 4096);
        gload16(b0, ldsB);
        gload16(b1, ldsB + 4096);
        a0 += 32; a1 += 32; b0 += 32; b1 += 32;
        __syncthreads();

        bf16x8 af[4], bfr[4];
#pragma unroll
        for (int mi = 0; mi < 4; ++mi)
            af[mi] = *(const bf16x8*)&Asm[(size_t)(((wr * 64 + mi * 16 + frow) * 32 + fk) ^ flip)];
#pragma unroll
        for (int ni = 0; ni < 4; ++ni)
            bfr[ni] = *(const bf16x8*)&Bsm[(size_t)(((wc * 64 + ni * 16 + frow) * 32 + fk) ^ flip)];
#pragma unroll
        for (int mi = 0; mi < 4; ++mi)
#pragma unroll
            for (int ni = 0; ni < 4; ++ni)
                acc[mi][ni] = mfma16(bfr[ni], af[mi], acc[mi][ni]);   // swapped
        __syncthreads();
    }

    // swapped-operand C/D layout: row = ..+frow, cols = ..+(lane>>4)*4 + r
    const int row0 = bm * 128 + wr * 64 + frow;
    const int col0 = bn * 128 + wc * 64 + (lane >> 4) * 4;

    if constexpr (EPI == 0) {
        bf16_t* C = (bf16_t*)Cv + (long)bz * sC;
#pragma unroll
        for (int mi = 0; mi < 4; ++mi)
#pragma unroll
            for (int ni = 0; ni < 4; ++ni) {
                bf16x4 o;
#pragma unroll
                for (int r = 0; r < 4; ++r) o[r] = (bf16_t)acc[mi][ni][r];
                *(bf16x4*)&C[(size_t)(row0 + mi * 16) * ldc + col0 + ni * 16] = o;
            }
    } else if constexpr (EPI == 1) {
        float* C = (float*)Cv + (long)bz * sC;
#pragma unroll
        for (int mi = 0; mi < 4; ++mi)
#pragma unroll
            for (int ni = 0; ni < 4; ++ni)
                *(f32x4*)&C[(size_t)(row0 + mi * 16) * ldc + col0 + ni * 16] = acc[mi][ni];
    } else {
        // scatter even rows, zero odd rows
        float* C = (float*)Cv;
        const f32x4 z4 = {0.f, 0.f, 0.f, 0.f};
#pragma unroll
        for (int mi = 0; mi < 4; ++mi)
#pragma unroll
            for (int ni = 0; ni < 4; ++ni) {
                const int m  = row0 + mi * 16;
                const int gr = ((m >> 11) << 12) | (((m >> 8) & 7) << 9) | ((m & 255) << 1);
                *(f32x4*)&C[(size_t)gr * 1024 + col0 + ni * 16]       = acc[mi][ni];
                *(f32x4*)&C[(size_t)(gr + 1) * 1024 + col0 + ni * 16] = z4;
            }
    }
}

// ---------- LayerNorm (in place, q and k slices only) ----------
__global__ __launch_bounds__(256)
void ln_kernel(bf16_t* __restrict__ qkv,
               const float* __restrict__ gamma, const float* __restrict__ beta)
{
    const int row = blockIdx.x;
    const int which = blockIdx.y;   // 0=q 1=k
    bf16_t* p = qkv + (size_t)row * 3072 + which * 1024;
    const int t = threadIdx.x;

    bf16x4 v = *(const bf16x4*)&p[t * 4];
    float f[4];
    float s = 0.f, ss = 0.f;
#pragma unroll
    for (int i = 0; i < 4; ++i) { f[i] = (float)v[i]; s += f[i]; ss += f[i] * f[i]; }
#pragma unroll
    for (int o = 32; o; o >>= 1) { s += __shfl_xor(s, o); ss += __shfl_xor(ss, o); }

    __shared__ float rs_[4], rss_[4];
    const int wave = t >> 6, lane = t & 63;
    if (lane == 0) { rs_[wave] = s; rss_[wave] = ss; }
    __syncthreads();
    s  = rs_[0] + rs_[1] + rs_[2] + rs_[3];
    ss = rss_[0] + rss_[1] + rss_[2] + rss_[3];

    const float mu   = s * (1.f / 1024.f);
    const float var  = ss * (1.f / 1024.f) - mu * mu;
    const float rstd = rsqrtf(var + 1e-5f);

    bf16x4 o;
#pragma unroll
    for (int i = 0; i < 4; ++i) {
        const int c = t * 4 + i;
        o[i] = (bf16_t)((f[i] - mu) * rstd * gamma[c] + beta[c]);
    }
    *(bf16x4*)&p[t * 4] = o;
}

// ---------- fused LayerNorm + transpose for V ----------
// block = (kb, seg): rows k = kb*32..+32 of segment seg.
// reads raw V rows from QKV (stride 3072), writes LN'd V^T to Vt[seg][e][k].
__global__ __launch_bounds__(256)
void ln_v_t(const bf16_t* __restrict__ qkv, bf16_t* __restrict__ Vt,
            const float* __restrict__ gamma, const float* __restrict__ beta)
{
    const int kb  = blockIdx.x;
    const int seg = blockIdx.y;
    const int t = threadIdx.x;
    const bf16_t* V = qkv + ((size_t)seg * 256 + kb * 32) * 3072 + 2048;

    // stats: 8 threads per row
    const int row = t >> 3, sub = t & 7;
    const bf16_t* vr = V + (size_t)row * 3072 + sub * 128;
    float s = 0.f, ss = 0.f;
#pragma unroll
    for (int i = 0; i < 16; ++i) {
        bf16x8 v = *(const bf16x8*)&vr[i * 8];
#pragma unroll
        for (int j = 0; j < 8; ++j) { float f = (float)v[j]; s += f; ss += f * f; }
    }
#pragma unroll
    for (int o = 1; o < 8; o <<= 1) { s += __shfl_xor(s, o); ss += __shfl_xor(ss, o); }
    __shared__ float mu_[32], rs_[32];
    if (sub == 0) {
        const float mu = s * (1.f / 1024.f);
        mu_[row] = mu;
        rs_[row] = rsqrtf(ss * (1.f / 1024.f) - mu * mu + 1e-5f);
    }
    __syncthreads();

    __shared__ bf16_t tile[32][33];
    const int xx = t & 31, yy = t >> 5;
    bf16_t* dst = Vt + (size_t)seg * 262144 + kb * 32;
    for (int e0 = 0; e0 < 1024; e0 += 32) {
        const float g = gamma[e0 + xx], b = beta[e0 + xx];
#pragma unroll
        for (int i = 0; i < 4; ++i) {
            const int r = yy * 4 + i;
            const float f = (float)V[(size_t)r * 3072 + e0 + xx];
            tile[r][xx] = (bf16_t)((f - mu_[r]) * rs_[r] * g + b);
        }
        __syncthreads();
#pragma unroll
        for (int i = 0; i < 4; ++i) {
            const int e = yy * 4 + i;
            dst[(size_t)(e0 + e) * 256 + xx] = tile[xx][e];
        }
        __syncthreads();
    }
}

// ---------- causal softmax: S[32*256][256] f32 -> P bf16 ----------
__global__ __launch_bounds__(256)
void softmax_kernel(const float* __restrict__ S, bf16_t* __restrict__ P)
{
    const int q = blockIdx.x & 255;
    const size_t base = (size_t)blockIdx.x * 256;
    const int c = threadIdx.x;
    const bool ok = (c <= q);

    float v = ok ? S[base + c] * (1.f / 32.f) : -3.0e38f;
    float m = v;
#pragma unroll
    for (int o = 32; o; o >>= 1) m = fmaxf(m, __shfl_xor(m, o));

    __shared__ float rm[4], rsum[4];
    const int wave = c >> 6, lane = c & 63;
    if (lane == 0) rm[wave] = m;
    __syncthreads();
    m = fmaxf(fmaxf(rm[0], rm[1]), fmaxf(rm[2], rm[3]));

    float e = ok ? __expf(v - m) : 0.f;
    float s = e;
#pragma unroll
    for (int o = 32; o; o >>= 1) s += __shfl_xor(s, o);
    if (lane == 0) rsum[wave] = s;
    __syncthreads();
    s = rsum[0] + rsum[1] + rsum[2] + rsum[3];

    P[base + c] = (bf16_t)(e / s);
}

// ---------- launch ----------

extern "C" void kernel_launch(void* const* d_in, const int* in_sizes, int n_in,
                              void* d_out, int out_size, void* d_ws, size_t ws_size,
                              hipStream_t stream)
{
    const float* x     = (const float*)d_in[0];
    const float* Wq    = (const float*)d_in[1];
    const float* Wk    = (const float*)d_in[2];
    const float* Wv    = (const float*)d_in[3];
    const float* Wo    = (const float*)d_in[4];
    const float* gamma = (const float*)d_in[5];
    const float* beta  = (const float*)d_in[6];
    float* out = (float*)d_out;

    char* ws = (char*)d_ws;
    bf16_t* Xe   = (bf16_t*)(ws);                  // 8192x1024 bf16   (16 MB)
    bf16_t* Wqkv = (bf16_t*)(ws + (16u  << 20));   // 3072x1024 bf16   ( 6 MB)
    bf16_t* Wob  = (bf16_t*)(ws + (22u  << 20));   // 1024x1024 bf16   ( 2 MB)
    bf16_t* QKV  = (bf16_t*)(ws + (24u  << 20));   // 8192x3072 bf16   (48 MB)
    float*  Smat = (float*) (ws + (72u  << 20));   // 32x256x256 f32   ( 8 MB)
    bf16_t* P    = (bf16_t*)(ws + (80u  << 20));   // 32x256x256 bf16  ( 4 MB)
    bf16_t* Vt   = (bf16_t*)(ws + (84u  << 20));   // 32x1024x256 bf16 (16 MB)
    bf16_t* Y    = (bf16_t*)(ws + (100u << 20));   // 8192x1024 bf16   (16 MB)

    // prep: weight casts + dilated gather
    cast_f32_bf16<<<1024, 256, 0, stream>>>(Wq, Wqkv,           262144);
    cast_f32_bf16<<<1024, 256, 0, stream>>>(Wk, Wqkv + 1048576, 262144);
    cast_f32_bf16<<<1024, 256, 0, stream>>>(Wv, Wqkv + 2097152, 262144);
    cast_f32_bf16<<<1024, 256, 0, stream>>>(Wo, Wob,            262144);
    gather_cast_x<<<8192, 256, 0, stream>>>(x, Xe);

    // QKV projection: [8192,1024] x [3072,1024]^T -> [8192,3072] bf16
    gemm256<0><<<dim3(12, 32), 512, 0, stream>>>(Xe, Wqkv, QKV, 1024, 1024, 1024, 3072);

    // LayerNorm q,k in place (v handled by ln_v_t)
    ln_kernel<<<dim3(8192, 2), 256, 0, stream>>>(QKV, gamma, beta);

    // S = Q K^T per segment
    gemm_nt<1><<<dim3(2, 2, 32), 256, 0, stream>>>(
        QKV, QKV + 1024, Smat, 1024, 3072, 3072, 256,
        256L * 3072, 256L * 3072, 65536L, 0);

    // causal softmax -> P bf16
    softmax_kernel<<<8192, 256, 0, stream>>>(Smat, P);

    // fused LN + transpose of V: QKV[.,2048+e] -> Vt[seg][e][k]
    ln_v_t<<<dim3(8, 32), 256, 0, stream>>>(QKV, Vt, gamma, beta);

    // Y = P V per segment (tri: bm==0 blocks only need K=128)
    gemm_nt<0><<<dim3(8, 2, 32), 256, 0, stream>>>(
        P, Vt, Y, 256, 256, 256, 1024,
        65536L, 262144L, 262144L, 1);

    // out = Y Wo^T scattered to even rows of d_out, odd rows zeroed
    gemm_nt<2><<<dim3(8, 64, 1), 256, 0, stream>>>(
        Y, Wob, out, 1024, 1024, 1024, 1024, 0, 0, 0, 0);
}

// Round 4
// 201.853 us; speedup vs baseline: 1.1142x; 1.1142x over previous
//
#include <hip/hip_runtime.h>
#include <stdint.h>

typedef __bf16 bf16_t;
typedef __bf16 bf16x8 __attribute__((ext_vector_type(8)));
typedef __bf16 bf16x4 __attribute__((ext_vector_type(4)));
typedef float  f32x4  __attribute__((ext_vector_type(4)));

// ---------- helpers ----------

__device__ __forceinline__ void gload16(const void* g, void* lds)
{
    __builtin_amdgcn_global_load_lds(
        (__attribute__((address_space(1))) void*)(void*)g,
        (__attribute__((address_space(3))) void*)lds,
        16, 0, 0);
}

// operands swapped at call sites (mfma(b,a,acc)) -> lane holds 4 CONSECUTIVE
// COLUMNS: C[row = lane&15 (A-frag row)][col = (lane>>4)*4 + r]
__device__ __forceinline__ f32x4 mfma16(bf16x8 a, bf16x8 b, f32x4 c)
{
    return __builtin_amdgcn_mfma_f32_16x16x32_bf16(a, b, c, 0, 0, 0);
}

#define SBAR()   asm volatile("s_barrier" ::: "memory")
#define LGKM0()  asm volatile("s_waitcnt lgkmcnt(0)" ::: "memory")
#define VMCNT(N) asm volatile("s_waitcnt vmcnt(" #N ")" ::: "memory")

// ---------- prep kernels ----------

// all 4 weight casts in one launch: 4096 blocks, 1024 elems each
__global__ __launch_bounds__(256)
void cast_weights(const float* __restrict__ Wq, const float* __restrict__ Wk,
                  const float* __restrict__ Wv, const float* __restrict__ Wo,
                  bf16_t* __restrict__ Wqkv, bf16_t* __restrict__ Wob)
{
    const int which = blockIdx.x >> 10;          // 0..3
    const int blk   = blockIdx.x & 1023;
    const float* src = which == 0 ? Wq : which == 1 ? Wk : which == 2 ? Wv : Wo;
    bf16_t* dst = which == 3 ? Wob : Wqkv + (size_t)which * 1048576;
    const size_t i = ((size_t)blk * 256 + threadIdx.x) * 4;
    float4 f = *(const float4*)&src[i];
    bf16x4 o;
    o[0] = (bf16_t)f.x; o[1] = (bf16_t)f.y; o[2] = (bf16_t)f.z; o[3] = (bf16_t)f.w;
    *(bf16x4*)&dst[i] = o;
}

__global__ __launch_bounds__(256)
void gather_cast_x(const float* __restrict__ x, bf16_t* __restrict__ Xe)
{
    const int m = blockIdx.x;
    const int b = m >> 11, g = (m >> 8) & 7, j = m & 255;
    const float* src = x + ((size_t)b * 4096 + g * 512 + 2 * j) * 1024;
    bf16_t* dst = Xe + (size_t)m * 1024;
    const int t = threadIdx.x;
    float4 f = *(const float4*)&src[t * 4];
    bf16x4 o;
    o[0] = (bf16_t)f.x; o[1] = (bf16_t)f.y; o[2] = (bf16_t)f.z; o[3] = (bf16_t)f.w;
    *(bf16x4*)&dst[t * 4] = o;
}

// ---------- 256x128 2-phase GEMM: C[M,N] = A[M,K] * B[N,K]^T ----------
// 512 thr = 8 waves (2M wr x 4N wc); per-wave out 128x32; BK=64.
// LDS 96KB double-buffered: per buf A 32KB (4 units q0..q3 of 64 rows) +
// B 16KB (2 units). Phase 1 reads A rows {wr*128+0..63}=q(2wr) + all B;
// phase 2 reads q(2wr+1). Stage discipline (regions provably read-complete):
//   P1(t): stage q1,q3 of t+1 (other-buf; last read P2 of t-1)
//   P2(t): stage q0,q2,B0,B1 of t+2 (cur-buf; read this tile in P1)
// vmcnt(6) at end of each phase:
//   end-P1 waits q1q3(t) [needed by P2(t)]; end-P2 waits q0q2B(t+1).
// LDS swizzle: 16B-granule bits (0,1,2) ^= (3,4,5)  [round-3 verified: 0 conflicts]
template<int EPI>   // 0 = store bf16 ; 2 = scatter f32 even rows + zero odd
__global__ __launch_bounds__(512, 2)
void gemm256x128(const bf16_t* __restrict__ A, const bf16_t* __restrict__ B,
                 void* __restrict__ Cv, int K, int lda, int ldb, int ldc)
{
    __shared__ __align__(16) char lds[98304];

    const int tid = threadIdx.x;
    const int w = tid >> 6, lane = tid & 63;
    const int wr = w >> 2, wc = w & 3;
    const int fr = lane & 15, fg = lane >> 4;
    const int bn = blockIdx.x, bm = blockIdx.y;
    const int NT = K >> 6;

    // stage side: one gload16 per 8KB unit; granule g=tid fetches global
    // granule s = g ^ ((g>>3)&7)  (inverse of the read-side XOR)
    const int s = tid ^ ((tid >> 3) & 7);
    const char* srcA = (const char*)A + ((size_t)(bm * 256 + (s >> 3)) * lda + (s & 7) * 8) * 2;
    const char* srcB = (const char*)B + ((size_t)(bn * 128 + (s >> 3)) * ldb + (s & 7) * 8) * 2;
    const size_t aStep = (size_t)64 * lda * 2;
    const size_t bStep = (size_t)64 * ldb * 2;
    const int ldsW = w * 1024;

#define STG_A(T, Q) gload16(srcA + (Q) * aStep + (size_t)(T) * 128, \
                            lds + ((T) & 1) * 49152 + (Q) * 8192 + ldsW)
#define STG_B(T, U) gload16(srcB + (U) * bStep + (size_t)(T) * 128, \
                            lds + ((T) & 1) * 49152 + 32768 + (U) * 8192 + ldsW)

    const int flip = (fr & 7) << 4;
    const int aoff = (wr * 128 + fr) * 128 + fg * 16;    // + ph*8192 + mi*2048 + ks*64
    const int boff = 32768 + (wc * 32 + fr) * 128 + fg * 16;

    bf16x8 a[4][2], b[2][2];
    f32x4 acc[8][2] = {};

#define LDA(PH, CB) do {                                                        \
    _Pragma("unroll") for (int mi = 0; mi < 4; ++mi)                            \
    _Pragma("unroll") for (int ks = 0; ks < 2; ++ks)                            \
        a[mi][ks] = *(const bf16x8*)(lds + (CB) +                               \
            ((aoff + (PH) * 8192 + mi * 2048 + ks * 64) ^ flip));               \
} while (0)

#define LDB(CB) do {                                                            \
    _Pragma("unroll") for (int ni = 0; ni < 2; ++ni)                            \
    _Pragma("unroll") for (int ks = 0; ks < 2; ++ks)                            \
        b[ni][ks] = *(const bf16x8*)(lds + (CB) +                               \
            ((boff + ni * 2048 + ks * 64) ^ flip));                             \
} while (0)

#define MF(PH) do {                                                             \
    _Pragma("unroll") for (int mi = 0; mi < 4; ++mi)                            \
    _Pragma("unroll") for (int ni = 0; ni < 2; ++ni)                            \
    _Pragma("unroll") for (int ks = 0; ks < 2; ++ks)                            \
        acc[(PH) * 4 + mi][ni] =                                                \
            mfma16(b[ni][ks], a[mi][ks], acc[(PH) * 4 + mi][ni]);               \
} while (0)

    // prologue: all 6 units of t0, then q0,q2,B0,B1 of t1; wait t0 complete
    STG_A(0, 0); STG_A(0, 1); STG_A(0, 2); STG_A(0, 3); STG_B(0, 0); STG_B(0, 1);
    STG_A(1, 0); STG_A(1, 2); STG_B(1, 0); STG_B(1, 1);
    VMCNT(4);
    SBAR();

    for (int t = 0; t < NT - 2; ++t) {
        const int cb = (t & 1) * 49152;
        // P1
        LDA(0, cb); LDB(cb);
        STG_A(t + 1, 1); STG_A(t + 1, 3);
        SBAR(); LGKM0();
        __builtin_amdgcn_s_setprio(1); MF(0); __builtin_amdgcn_s_setprio(0);
        VMCNT(6);
        SBAR();
        // P2
        LDA(1, cb);
        STG_A(t + 2, 0); STG_A(t + 2, 2); STG_B(t + 2, 0); STG_B(t + 2, 1);
        SBAR(); LGKM0();
        __builtin_amdgcn_s_setprio(1); MF(1); __builtin_amdgcn_s_setprio(0);
        VMCNT(6);
        SBAR();
    }

    // tile NT-2: stage only q1q3(NT-1); drain fully at end
    {
        const int cb = ((NT - 2) & 1) * 49152;
        LDA(0, cb); LDB(cb);
        STG_A(NT - 1, 1); STG_A(NT - 1, 3);
        SBAR(); LGKM0();
        MF(0);
        VMCNT(6);
        SBAR();
        LDA(1, cb);
        SBAR(); LGKM0();
        MF(1);
        VMCNT(0);
        SBAR();
    }
    // tile NT-1: everything resident; no stages, no barriers needed
    {
        const int cb = ((NT - 1) & 1) * 49152;
        LDA(0, cb); LDB(cb);
        LGKM0();
        MF(0);
        LDA(1, cb);
        LGKM0();
        MF(1);
    }

#undef STG_A
#undef STG_B
#undef LDA
#undef LDB
#undef MF

    // epilogue: row = r0 + (mig>>2)*64 + (mig&3)*16 ; col = c0 + ni*16 (+4 packed)
    const int r0 = bm * 256 + wr * 128 + fr;
    const int c0 = bn * 128 + wc * 32 + fg * 4;
    if constexpr (EPI == 0) {
        bf16_t* C = (bf16_t*)Cv;
#pragma unroll
        for (int mig = 0; mig < 8; ++mig)
#pragma unroll
            for (int ni = 0; ni < 2; ++ni) {
                const int row = r0 + (mig >> 2) * 64 + (mig & 3) * 16;
                bf16x4 o;
#pragma unroll
                for (int r = 0; r < 4; ++r) o[r] = (bf16_t)acc[mig][ni][r];
                *(bf16x4*)&C[(size_t)row * ldc + c0 + ni * 16] = o;
            }
    } else {
        // scatter even rows of d_out, zero odd rows
        float* C = (float*)Cv;
        const f32x4 z4 = {0.f, 0.f, 0.f, 0.f};
#pragma unroll
        for (int mig = 0; mig < 8; ++mig)
#pragma unroll
            for (int ni = 0; ni < 2; ++ni) {
                const int m  = r0 + (mig >> 2) * 64 + (mig & 3) * 16;
                const int gr = ((m >> 11) << 12) | (((m >> 8) & 7) << 9) | ((m & 255) << 1);
                *(f32x4*)&C[(size_t)gr * 1024 + c0 + ni * 16]       = acc[mig][ni];
                *(f32x4*)&C[(size_t)(gr + 1) * 1024 + c0 + ni * 16] = z4;
            }
    }
}

// ---------- GEMM: C[M,N] = A[M,K] * B[N,K]^T (128x128 tile, swizzled m97) ----------
// flags: bit0 = triangular-A K-skip (bm==0 -> K/2); bit1 = skip bn>bm blocks.
// EPI: 0 = store bf16, 1 = store f32.
template<int EPI>
__global__ __launch_bounds__(256)
void gemm_nt(const bf16_t* __restrict__ A, const bf16_t* __restrict__ B,
             void* __restrict__ Cv,
             int K, int lda, int ldb, int ldc,
             long sA, long sB, long sC, int flags)
{
    __shared__ __align__(16) bf16_t Asm[128 * 32];
    __shared__ __align__(16) bf16_t Bsm[128 * 32];

    const int bn = blockIdx.x, bm = blockIdx.y, bz = blockIdx.z;
    if ((flags & 2) && bn > bm) return;

    const int tid  = threadIdx.x;
    const int wave = tid >> 6;
    const int lane = tid & 63;
    const int wr = wave >> 1, wc = wave & 1;

    const bf16_t* Ab = A + (long)bz * sA;
    const bf16_t* Bb = B + (long)bz * sB;

    const int Keff = ((flags & 1) && bm == 0) ? (K >> 1) : K;

    const int sw0 = tid ^ ((tid >> 3) & 3);
    const int dd1 = tid + 256;
    const int sw1 = dd1 ^ ((dd1 >> 3) & 3);
    const bf16_t* a0 = Ab + (size_t)(bm * 128 + (sw0 >> 2)) * lda + (sw0 & 3) * 8;
    const bf16_t* a1 = Ab + (size_t)(bm * 128 + (sw1 >> 2)) * lda + (sw1 & 3) * 8;
    const bf16_t* b0 = Bb + (size_t)(bn * 128 + (sw0 >> 2)) * ldb + (sw0 & 3) * 8;
    const bf16_t* b1 = Bb + (size_t)(bn * 128 + (sw1 >> 2)) * ldb + (sw1 & 3) * 8;
    char* ldsA = (char*)Asm + wave * 1024;
    char* ldsB = (char*)Bsm + wave * 1024;

    f32x4 acc[4][4] = {};

    const int frow = lane & 15;
    const int fk   = (lane >> 4) * 8;
    const int flip = (frow & 6) << 2;

    for (int k0 = 0; k0 < Keff; k0 += 32) {
        gload16(a0, ldsA);
        gload16(a1, ldsA + 4096);
        gload16(b0, ldsB);
        gload16(b1, ldsB + 4096);
        a0 += 32; a1 += 32; b0 += 32; b1 += 32;
        __syncthreads();

        bf16x8 af[4], bfr[4];
#pragma unroll
        for (int mi = 0; mi < 4; ++mi)
            af[mi] = *(const bf16x8*)&Asm[(size_t)(((wr * 64 + mi * 16 + frow) * 32 + fk) ^ flip)];
#pragma unroll
        for (int ni = 0; ni < 4; ++ni)
            bfr[ni] = *(const bf16x8*)&Bsm[(size_t)(((wc * 64 + ni * 16 + frow) * 32 + fk) ^ flip)];
#pragma unroll
        for (int mi = 0; mi < 4; ++mi)
#pragma unroll
            for (int ni = 0; ni < 4; ++ni)
                acc[mi][ni] = mfma16(bfr[ni], af[mi], acc[mi][ni]);   // swapped
        __syncthreads();
    }

    const int row0 = bm * 128 + wr * 64 + frow;
    const int col0 = bn * 128 + wc * 64 + (lane >> 4) * 4;

    if constexpr (EPI == 0) {
        bf16_t* C = (bf16_t*)Cv + (long)bz * sC;
#pragma unroll
        for (int mi = 0; mi < 4; ++mi)
#pragma unroll
            for (int ni = 0; ni < 4; ++ni) {
                bf16x4 o;
#pragma unroll
                for (int r = 0; r < 4; ++r) o[r] = (bf16_t)acc[mi][ni][r];
                *(bf16x4*)&C[(size_t)(row0 + mi * 16) * ldc + col0 + ni * 16] = o;
            }
    } else {
        float* C = (float*)Cv + (long)bz * sC;
#pragma unroll
        for (int mi = 0; mi < 4; ++mi)
#pragma unroll
            for (int ni = 0; ni < 4; ++ni)
                *(f32x4*)&C[(size_t)(row0 + mi * 16) * ldc + col0 + ni * 16] = acc[mi][ni];
    }
}

// ---------- LayerNorm (in place on bf16 QKV rows, D=1024) ----------
__global__ __launch_bounds__(256)
void ln_kernel(bf16_t* __restrict__ qkv,
               const float* __restrict__ gamma, const float* __restrict__ beta)
{
    const int row = blockIdx.x;
    const int which = blockIdx.y;   // 0=q 1=k 2=v
    bf16_t* p = qkv + (size_t)row * 3072 + which * 1024;
    const int t = threadIdx.x;

    bf16x4 v = *(const bf16x4*)&p[t * 4];
    float f[4];
    float s = 0.f, ss = 0.f;
#pragma unroll
    for (int i = 0; i < 4; ++i) { f[i] = (float)v[i]; s += f[i]; ss += f[i] * f[i]; }
#pragma unroll
    for (int o = 32; o; o >>= 1) { s += __shfl_xor(s, o); ss += __shfl_xor(ss, o); }

    __shared__ float rs_[4], rss_[4];
    const int wave = t >> 6, lane = t & 63;
    if (lane == 0) { rs_[wave] = s; rss_[wave] = ss; }
    __syncthreads();
    s  = rs_[0] + rs_[1] + rs_[2] + rs_[3];
    ss = rss_[0] + rss_[1] + rss_[2] + rss_[3];

    const float mu   = s * (1.f / 1024.f);
    const float var  = ss * (1.f / 1024.f) - mu * mu;
    const float rstd = rsqrtf(var + 1e-5f);

    bf16x4 o;
#pragma unroll
    for (int i = 0; i < 4; ++i) {
        const int c = t * 4 + i;
        o[i] = (bf16_t)((f[i] - mu) * rstd * gamma[c] + beta[c]);
    }
    *(bf16x4*)&p[t * 4] = o;
}

// ---------- causal softmax: S[32*256][256] f32 -> P bf16 ----------
__global__ __launch_bounds__(256)
void softmax_kernel(const float* __restrict__ S, bf16_t* __restrict__ P)
{
    const int q = blockIdx.x & 255;
    const size_t base = (size_t)blockIdx.x * 256;
    const int c = threadIdx.x;
    const bool ok = (c <= q);

    float v = ok ? S[base + c] * (1.f / 32.f) : -3.0e38f;
    float m = v;
#pragma unroll
    for (int o = 32; o; o >>= 1) m = fmaxf(m, __shfl_xor(m, o));

    __shared__ float rm[4], rsum[4];
    const int wave = c >> 6, lane = c & 63;
    if (lane == 0) rm[wave] = m;
    __syncthreads();
    m = fmaxf(fmaxf(rm[0], rm[1]), fmaxf(rm[2], rm[3]));

    float e = ok ? __expf(v - m) : 0.f;
    float s = e;
#pragma unroll
    for (int o = 32; o; o >>= 1) s += __shfl_xor(s, o);
    if (lane == 0) rsum[wave] = s;
    __syncthreads();
    s = rsum[0] + rsum[1] + rsum[2] + rsum[3];

    P[base + c] = (bf16_t)(e / s);
}

// ---------- V transpose per segment: Vn[k][e] (stride 3072) -> Vt[seg][e][k] ----------
__global__ __launch_bounds__(256)
void transpose_v(const bf16_t* __restrict__ Vn, bf16_t* __restrict__ Vt)
{
    __shared__ bf16_t tile[32][33];
    const int seg = blockIdx.z;
    const int e0 = blockIdx.x * 32, k0 = blockIdx.y * 32;
    const int xx = threadIdx.x, yy = threadIdx.y;
    const bf16_t* src = Vn + (size_t)seg * 256 * 3072;
#pragma unroll
    for (int i = 0; i < 32; i += 8)
        tile[yy + i][xx] = src[(size_t)(k0 + yy + i) * 3072 + e0 + xx];
    __syncthreads();
    bf16_t* dst = Vt + (size_t)seg * 262144;
#pragma unroll
    for (int i = 0; i < 32; i += 8)
        dst[(size_t)(e0 + yy + i) * 256 + k0 + xx] = tile[xx][yy + i];
}

// ---------- launch ----------

extern "C" void kernel_launch(void* const* d_in, const int* in_sizes, int n_in,
                              void* d_out, int out_size, void* d_ws, size_t ws_size,
                              hipStream_t stream)
{
    const float* x     = (const float*)d_in[0];
    const float* Wq    = (const float*)d_in[1];
    const float* Wk    = (const float*)d_in[2];
    const float* Wv    = (const float*)d_in[3];
    const float* Wo    = (const float*)d_in[4];
    const float* gamma = (const float*)d_in[5];
    const float* beta  = (const float*)d_in[6];
    float* out = (float*)d_out;

    char* ws = (char*)d_ws;
    bf16_t* Xe   = (bf16_t*)(ws);                  // 8192x1024 bf16   (16 MB)
    bf16_t* Wqkv = (bf16_t*)(ws + (16u  << 20));   // 3072x1024 bf16   ( 6 MB)
    bf16_t* Wob  = (bf16_t*)(ws + (22u  << 20));   // 1024x1024 bf16   ( 2 MB)
    bf16_t* QKV  = (bf16_t*)(ws + (24u  << 20));   // 8192x3072 bf16   (48 MB)
    float*  Smat = (float*) (ws + (72u  << 20));   // 32x256x256 f32   ( 8 MB)
    bf16_t* P    = (bf16_t*)(ws + (80u  << 20));   // 32x256x256 bf16  ( 4 MB)
    bf16_t* Vt   = (bf16_t*)(ws + (84u  << 20));   // 32x1024x256 bf16 (16 MB)
    bf16_t* Y    = (bf16_t*)(ws + (100u << 20));   // 8192x1024 bf16   (16 MB)

    // prep: fused weight casts + dilated gather
    cast_weights<<<4096, 256, 0, stream>>>(Wq, Wk, Wv, Wo, Wqkv, Wob);
    gather_cast_x<<<8192, 256, 0, stream>>>(x, Xe);

    // QKV projection: [8192,1024] x [3072,1024]^T -> [8192,3072] bf16
    // 768 blocks = exactly 3/CU
    gemm256x128<0><<<dim3(24, 32), 512, 0, stream>>>(
        Xe, Wqkv, QKV, 1024, 1024, 1024, 3072);

    // LayerNorm q,k,v in place
    ln_kernel<<<dim3(8192, 3), 256, 0, stream>>>(QKV, gamma, beta);

    // S = Q K^T per segment (skip fully-masked upper block bn>bm)
    gemm_nt<1><<<dim3(2, 2, 32), 256, 0, stream>>>(
        QKV, QKV + 1024, Smat, 1024, 3072, 3072, 256,
        256L * 3072, 256L * 3072, 65536L, 2);

    // causal softmax -> P bf16
    softmax_kernel<<<8192, 256, 0, stream>>>(Smat, P);

    // V transpose: [256,1024] -> [1024,256] per segment
    transpose_v<<<dim3(32, 8, 32), dim3(32, 8), 0, stream>>>(QKV + 2048, Vt);

    // Y = P V per segment (tri: bm==0 blocks only need K=128)
    gemm_nt<0><<<dim3(8, 2, 32), 256, 0, stream>>>(
        P, Vt, Y, 256, 256, 256, 1024,
        65536L, 262144L, 262144L, 1);

    // out = Y Wo^T scattered to even rows of d_out, odd rows zeroed
    // 256 blocks = exactly 1/CU
    gemm256x128<2><<<dim3(8, 32), 512, 0, stream>>>(
        Y, Wob, out, 1024, 1024, 1024, 1024);
}

// Round 5
// 173.828 us; speedup vs baseline: 1.2938x; 1.1612x over previous
//
#include <hip/hip_runtime.h>
#include <stdint.h>

typedef __bf16 bf16_t;
typedef __bf16 bf16x8 __attribute__((ext_vector_type(8)));
typedef __bf16 bf16x4 __attribute__((ext_vector_type(4)));
typedef float  f32x4  __attribute__((ext_vector_type(4)));

// ---------- helpers ----------

__device__ __forceinline__ void gload16(const void* g, void* lds)
{
    __builtin_amdgcn_global_load_lds(
        (__attribute__((address_space(1))) void*)(void*)g,
        (__attribute__((address_space(3))) void*)lds,
        16, 0, 0);
}

// operands swapped at call sites (mfma(b,a,acc)) -> lane holds 4 CONSECUTIVE
// COLUMNS: C[row = lane&15 (A-frag row)][col = (lane>>4)*4 + r]
__device__ __forceinline__ f32x4 mfma16(bf16x8 a, bf16x8 b, f32x4 c)
{
    return __builtin_amdgcn_mfma_f32_16x16x32_bf16(a, b, c, 0, 0, 0);
}

#define SBAR()   asm volatile("s_barrier" ::: "memory")
#define LGKM0()  asm volatile("s_waitcnt lgkmcnt(0)" ::: "memory")
#define VMCNT(N) asm volatile("s_waitcnt vmcnt(" #N ")" ::: "memory")

// ---------- prep: fused weight casts + dilated gather ----------

__global__ __launch_bounds__(256)
void prep_kernel(const float* __restrict__ Wq, const float* __restrict__ Wk,
                 const float* __restrict__ Wv, const float* __restrict__ Wo,
                 const float* __restrict__ x,
                 bf16_t* __restrict__ Wqkv, bf16_t* __restrict__ Wob,
                 bf16_t* __restrict__ Xe)
{
    const int bid = blockIdx.x;
    const int t = threadIdx.x;
    if (bid < 4096) {
        const int which = bid >> 10;
        const int blk = bid & 1023;
        const float* src = which == 0 ? Wq : which == 1 ? Wk : which == 2 ? Wv : Wo;
        bf16_t* dst = which == 3 ? Wob : Wqkv + (size_t)which * 1048576;
        const size_t i = ((size_t)blk * 256 + t) * 4;
        float4 f = *(const float4*)&src[i];
        bf16x4 o;
        o[0] = (bf16_t)f.x; o[1] = (bf16_t)f.y; o[2] = (bf16_t)f.z; o[3] = (bf16_t)f.w;
        *(bf16x4*)&dst[i] = o;
    } else {
        const int m = bid - 4096;
        const int b = m >> 11, g = (m >> 8) & 7, j = m & 255;
        const float* src = x + ((size_t)b * 4096 + g * 512 + 2 * j) * 1024;
        bf16_t* dst = Xe + (size_t)m * 1024;
        float4 f = *(const float4*)&src[t * 4];
        bf16x4 o;
        o[0] = (bf16_t)f.x; o[1] = (bf16_t)f.y; o[2] = (bf16_t)f.z; o[3] = (bf16_t)f.w;
        *(bf16x4*)&dst[t * 4] = o;
    }
}

// ---------- persistent 256x128 GEMM (K=1024 fixed, 16 K-tiles per sub-tile) ----------
// grid (8,32) = 256 blocks = 1/CU. Each block: one bm (256 rows), NSUB bn
// sub-tiles (128 cols each, bn = j*NSUB+s). Pipeline stays hot across
// sub-tile boundaries; mid-epilogue after the boundary vmcnt(6).
// XCD-chunked swizzle: dispatch id -> logical L = (id%8)*32 + id/8 so each
// XCD gets 4 consecutive bm rows (A-panels 2MB, fits 4MB L2).
// 2-phase/K-tile, counted vmcnt(6), LDS swizzle (granule bits 0-2 ^= 3-5,
// verified 0 conflicts in round 3).
// EPI: 0 = store bf16; 2 = scatter f32 to even rows of d_out + zero odd rows.
template<int EPI, int NSUB>
__global__ __launch_bounds__(512, 2)
void gemm_mt(const bf16_t* __restrict__ A, const bf16_t* __restrict__ B,
             void* __restrict__ Cv, int lda, int ldb, int ldc)
{
    __shared__ __align__(16) char lds[98304];

    const int tid = threadIdx.x;
    const int w = tid >> 6, lane = tid & 63;
    const int wr = w >> 2, wc = w & 3;
    const int fr = lane & 15, fg = lane >> 4;

    const int lin = blockIdx.y * 8 + blockIdx.x;
    const int L = (lin & 7) * 32 + (lin >> 3);
    const int bm = L >> 3, j = L & 7;
    const int NT = NSUB * 16;

    const int s = tid ^ ((tid >> 3) & 7);
    const char* srcA  = (const char*)A + ((size_t)(bm * 256 + (s >> 3)) * lda + (s & 7) * 8) * 2;
    const char* srcB0 = (const char*)B + ((size_t)(j * NSUB * 128 + (s >> 3)) * ldb + (s & 7) * 8) * 2;
    const size_t aStep  = (size_t)64 * lda * 2;
    const size_t bStep  = (size_t)64 * ldb * 2;
    const size_t bnStep = (size_t)128 * ldb * 2;
    const int ldsW = w * 1024;

#define STG_A(T, Q) gload16(srcA + (Q) * aStep + (size_t)((T) & 15) * 128,          \
                            lds + ((T) & 1) * 49152 + (Q) * 8192 + ldsW)
#define STG_B(T, U) gload16(srcB0 + (size_t)((T) >> 4) * bnStep + (U) * bStep       \
                                  + (size_t)((T) & 15) * 128,                        \
                            lds + ((T) & 1) * 49152 + 32768 + (U) * 8192 + ldsW)

    const int flip = (fr & 7) << 4;
    const int aoff = (wr * 128 + fr) * 128 + fg * 16;
    const int boff = 32768 + (wc * 32 + fr) * 128 + fg * 16;

    bf16x8 a[4][2], b[2][2];
    f32x4 acc[8][2] = {};

#define LDA(PH, CB) do {                                                        \
    _Pragma("unroll") for (int mi = 0; mi < 4; ++mi)                            \
    _Pragma("unroll") for (int ks = 0; ks < 2; ++ks)                            \
        a[mi][ks] = *(const bf16x8*)(lds + (CB) +                               \
            ((aoff + (PH) * 8192 + mi * 2048 + ks * 64) ^ flip));               \
} while (0)

#define LDB(CB) do {                                                            \
    _Pragma("unroll") for (int ni = 0; ni < 2; ++ni)                            \
    _Pragma("unroll") for (int ks = 0; ks < 2; ++ks)                            \
        b[ni][ks] = *(const bf16x8*)(lds + (CB) +                               \
            ((boff + ni * 2048 + ks * 64) ^ flip));                             \
} while (0)

#define MF(PH) do {                                                             \
    _Pragma("unroll") for (int mi = 0; mi < 4; ++mi)                            \
    _Pragma("unroll") for (int ni = 0; ni < 2; ++ni)                            \
    _Pragma("unroll") for (int ks = 0; ks < 2; ++ks)                            \
        acc[(PH) * 4 + mi][ni] =                                                \
            mfma16(b[ni][ks], a[mi][ks], acc[(PH) * 4 + mi][ni]);               \
} while (0)

    const int r0 = bm * 256 + wr * 128 + fr;
    const int c0w = wc * 32 + fg * 4;

#define DO_EPI(SUB) do {                                                                  \
    const int _c0 = (j * NSUB + (SUB)) * 128 + c0w;                                       \
    if constexpr (EPI == 0) {                                                             \
        bf16_t* C = (bf16_t*)Cv;                                                          \
        _Pragma("unroll") for (int mig = 0; mig < 8; ++mig)                               \
        _Pragma("unroll") for (int ni = 0; ni < 2; ++ni) {                                \
            const int row = r0 + (mig >> 2) * 64 + (mig & 3) * 16;                        \
            bf16x4 o;                                                                     \
            _Pragma("unroll") for (int r = 0; r < 4; ++r) o[r] = (bf16_t)acc[mig][ni][r]; \
            *(bf16x4*)&C[(size_t)row * ldc + _c0 + ni * 16] = o;                          \
        }                                                                                 \
    } else {                                                                              \
        float* C = (float*)Cv;                                                            \
        const f32x4 z4 = {0.f, 0.f, 0.f, 0.f};                                            \
        _Pragma("unroll") for (int mig = 0; mig < 8; ++mig)                               \
        _Pragma("unroll") for (int ni = 0; ni < 2; ++ni) {                                \
            const int m  = r0 + (mig >> 2) * 64 + (mig & 3) * 16;                         \
            const int gr = ((m >> 11) << 12) | (((m >> 8) & 7) << 9) | ((m & 255) << 1);  \
            *(f32x4*)&C[(size_t)gr * 1024 + _c0 + ni * 16]       = acc[mig][ni];          \
            *(f32x4*)&C[(size_t)(gr + 1) * 1024 + _c0 + ni * 16] = z4;                    \
        }                                                                                 \
    }                                                                                     \
    _Pragma("unroll") for (int mig = 0; mig < 8; ++mig)                                   \
    _Pragma("unroll") for (int ni = 0; ni < 2; ++ni)                                      \
        acc[mig][ni] = (f32x4){0.f, 0.f, 0.f, 0.f};                                       \
} while (0)

    // prologue: all 6 units of t0, then q0,q2,B0,B1 of t1; wait t0 complete
    STG_A(0, 0); STG_A(0, 1); STG_A(0, 2); STG_A(0, 3); STG_B(0, 0); STG_B(0, 1);
    STG_A(1, 0); STG_A(1, 2); STG_B(1, 0); STG_B(1, 1);
    VMCNT(4);
    SBAR();

    for (int t = 0; t < NT - 2; ++t) {
        const int cb = (t & 1) * 49152;
        // P1
        LDA(0, cb); LDB(cb);
        STG_A(t + 1, 1); STG_A(t + 1, 3);
        SBAR(); LGKM0();
        __builtin_amdgcn_s_setprio(1); MF(0); __builtin_amdgcn_s_setprio(0);
        VMCNT(6);
        SBAR();
        // P2
        LDA(1, cb);
        STG_A(t + 2, 0); STG_A(t + 2, 2); STG_B(t + 2, 0); STG_B(t + 2, 1);
        SBAR(); LGKM0();
        __builtin_amdgcn_s_setprio(1); MF(1); __builtin_amdgcn_s_setprio(0);
        VMCNT(6);
        if ((t & 15) == 15) DO_EPI(t >> 4);   // sub-tile boundary epilogue
        SBAR();
    }

    // tile NT-2: stage only q1q3(NT-1); drain fully at end
    {
        const int cb = ((NT - 2) & 1) * 49152;
        LDA(0, cb); LDB(cb);
        STG_A(NT - 1, 1); STG_A(NT - 1, 3);
        SBAR(); LGKM0();
        MF(0);
        VMCNT(6);
        SBAR();
        LDA(1, cb);
        SBAR(); LGKM0();
        MF(1);
        VMCNT(0);
        SBAR();
    }
    // tile NT-1: everything resident
    {
        const int cb = ((NT - 1) & 1) * 49152;
        LDA(0, cb); LDB(cb);
        LGKM0();
        MF(0);
        LDA(1, cb);
        LGKM0();
        MF(1);
    }
    DO_EPI(NSUB - 1);

#undef STG_A
#undef STG_B
#undef LDA
#undef LDB
#undef MF
#undef DO_EPI
}

// ---------- GEMM: C[M,N] = A[M,K] * B[N,K]^T (128x128 tile, swizzled m97) ----------
// flags bit0 = triangular-A K-skip (bm==0 -> K/2). Used for PV.
template<int EPI>   // 0 = store bf16, 1 = store f32
__global__ __launch_bounds__(256)
void gemm_nt(const bf16_t* __restrict__ A, const bf16_t* __restrict__ B,
             void* __restrict__ Cv,
             int K, int lda, int ldb, int ldc,
             long sA, long sB, long sC, int flags)
{
    __shared__ __align__(16) bf16_t Asm[128 * 32];
    __shared__ __align__(16) bf16_t Bsm[128 * 32];

    const int bn = blockIdx.x, bm = blockIdx.y, bz = blockIdx.z;
    const int tid  = threadIdx.x;
    const int wave = tid >> 6;
    const int lane = tid & 63;
    const int wr = wave >> 1, wc = wave & 1;

    const bf16_t* Ab = A + (long)bz * sA;
    const bf16_t* Bb = B + (long)bz * sB;

    const int Keff = ((flags & 1) && bm == 0) ? (K >> 1) : K;

    const int sw0 = tid ^ ((tid >> 3) & 3);
    const int dd1 = tid + 256;
    const int sw1 = dd1 ^ ((dd1 >> 3) & 3);
    const bf16_t* a0 = Ab + (size_t)(bm * 128 + (sw0 >> 2)) * lda + (sw0 & 3) * 8;
    const bf16_t* a1 = Ab + (size_t)(bm * 128 + (sw1 >> 2)) * lda + (sw1 & 3) * 8;
    const bf16_t* b0 = Bb + (size_t)(bn * 128 + (sw0 >> 2)) * ldb + (sw0 & 3) * 8;
    const bf16_t* b1 = Bb + (size_t)(bn * 128 + (sw1 >> 2)) * ldb + (sw1 & 3) * 8;
    char* ldsA = (char*)Asm + wave * 1024;
    char* ldsB = (char*)Bsm + wave * 1024;

    f32x4 acc[4][4] = {};

    const int frow = lane & 15;
    const int fk   = (lane >> 4) * 8;
    const int flip = (frow & 6) << 2;

    for (int k0 = 0; k0 < Keff; k0 += 32) {
        gload16(a0, ldsA);
        gload16(a1, ldsA + 4096);
        gload16(b0, ldsB);
        gload16(b1, ldsB + 4096);
        a0 += 32; a1 += 32; b0 += 32; b1 += 32;
        __syncthreads();

        bf16x8 af[4], bfr[4];
#pragma unroll
        for (int mi = 0; mi < 4; ++mi)
            af[mi] = *(const bf16x8*)&Asm[(size_t)(((wr * 64 + mi * 16 + frow) * 32 + fk) ^ flip)];
#pragma unroll
        for (int ni = 0; ni < 4; ++ni)
            bfr[ni] = *(const bf16x8*)&Bsm[(size_t)(((wc * 64 + ni * 16 + frow) * 32 + fk) ^ flip)];
#pragma unroll
        for (int mi = 0; mi < 4; ++mi)
#pragma unroll
            for (int ni = 0; ni < 4; ++ni)
                acc[mi][ni] = mfma16(bfr[ni], af[mi], acc[mi][ni]);   // swapped
        __syncthreads();
    }

    const int row0 = bm * 128 + wr * 64 + frow;
    const int col0 = bn * 128 + wc * 64 + (lane >> 4) * 4;

    if constexpr (EPI == 0) {
        bf16_t* C = (bf16_t*)Cv + (long)bz * sC;
#pragma unroll
        for (int mi = 0; mi < 4; ++mi)
#pragma unroll
            for (int ni = 0; ni < 4; ++ni) {
                bf16x4 o;
#pragma unroll
                for (int r = 0; r < 4; ++r) o[r] = (bf16_t)acc[mi][ni][r];
                *(bf16x4*)&C[(size_t)(row0 + mi * 16) * ldc + col0 + ni * 16] = o;
            }
    } else {
        float* C = (float*)Cv + (long)bz * sC;
#pragma unroll
        for (int mi = 0; mi < 4; ++mi)
#pragma unroll
            for (int ni = 0; ni < 4; ++ni)
                *(f32x4*)&C[(size_t)(row0 + mi * 16) * ldc + col0 + ni * 16] = acc[mi][ni];
    }
}

// ---------- merged: QK^T GEMM (blocks 0..95) + V transpose 64x64 (rest) ----------
// QK block id = seg*3 + r, (bm,bn) = [(0,0),(1,0),(1,1)][r] (causal skip).
// Transpose: id2 = bid-96: seg = id2>>6, eb = (id2&63)>>2, kb = id2&3.
__global__ __launch_bounds__(256)
void qk_tr_kernel(const bf16_t* __restrict__ qkv, float* __restrict__ Smat,
                  bf16_t* __restrict__ Vt)
{
    __shared__ __align__(16) char smem[16384];
    const int bid = blockIdx.x;
    const int tid = threadIdx.x;

    if (bid < 96) {
        const int seg = bid / 3, r = bid % 3;
        const int bm = (r + 1) >> 1, bn = r >> 1;
        const bf16_t* Ab = qkv + (size_t)seg * 256 * 3072;          // Q
        const bf16_t* Bb = Ab + 1024;                                // K
        bf16_t* Asm = (bf16_t*)smem;
        bf16_t* Bsm = Asm + 4096;

        const int wave = tid >> 6, lane = tid & 63;
        const int wr = wave >> 1, wc = wave & 1;
        const int sw0 = tid ^ ((tid >> 3) & 3);
        const int dd1 = tid + 256;
        const int sw1 = dd1 ^ ((dd1 >> 3) & 3);
        const bf16_t* a0 = Ab + (size_t)(bm * 128 + (sw0 >> 2)) * 3072 + (sw0 & 3) * 8;
        const bf16_t* a1 = Ab + (size_t)(bm * 128 + (sw1 >> 2)) * 3072 + (sw1 & 3) * 8;
        const bf16_t* b0 = Bb + (size_t)(bn * 128 + (sw0 >> 2)) * 3072 + (sw0 & 3) * 8;
        const bf16_t* b1 = Bb + (size_t)(bn * 128 + (sw1 >> 2)) * 3072 + (sw1 & 3) * 8;
        char* ldsA = (char*)Asm + wave * 1024;
        char* ldsB = (char*)Bsm + wave * 1024;

        f32x4 acc[4][4] = {};
        const int frow = lane & 15;
        const int fk   = (lane >> 4) * 8;
        const int flip = (frow & 6) << 2;

        for (int k0 = 0; k0 < 1024; k0 += 32) {
            gload16(a0, ldsA);
            gload16(a1, ldsA + 4096);
            gload16(b0, ldsB);
            gload16(b1, ldsB + 4096);
            a0 += 32; a1 += 32; b0 += 32; b1 += 32;
            __syncthreads();

            bf16x8 af[4], bfr[4];
#pragma unroll
            for (int mi = 0; mi < 4; ++mi)
                af[mi] = *(const bf16x8*)&Asm[(size_t)(((wr * 64 + mi * 16 + frow) * 32 + fk) ^ flip)];
#pragma unroll
            for (int ni = 0; ni < 4; ++ni)
                bfr[ni] = *(const bf16x8*)&Bsm[(size_t)(((wc * 64 + ni * 16 + frow) * 32 + fk) ^ flip)];
#pragma unroll
            for (int mi = 0; mi < 4; ++mi)
#pragma unroll
                for (int ni = 0; ni < 4; ++ni)
                    acc[mi][ni] = mfma16(bfr[ni], af[mi], acc[mi][ni]);
            __syncthreads();
        }

        float* C = Smat + (size_t)seg * 65536;
        const int row0 = bm * 128 + wr * 64 + frow;
        const int col0 = bn * 128 + wc * 64 + (lane >> 4) * 4;
#pragma unroll
        for (int mi = 0; mi < 4; ++mi)
#pragma unroll
            for (int ni = 0; ni < 4; ++ni)
                *(f32x4*)&C[(size_t)(row0 + mi * 16) * 256 + col0 + ni * 16] = acc[mi][ni];
    } else {
        // 64x64 transpose of LN'd V: qkv[seg][k][2048+e] -> Vt[seg][e][k]
        const int id2 = bid - 96;
        const int seg = id2 >> 6;
        const int rem = id2 & 63;
        const int eb = rem >> 2, kb = rem & 3;
        bf16_t* tile = (bf16_t*)smem;   // [64][65]

        const int rr = tid >> 2, cs = (tid & 3) * 16;
        const bf16_t* src = qkv + ((size_t)(seg * 256 + kb * 64 + rr)) * 3072
                                + 2048 + eb * 64 + cs;
        bf16x8 v0 = *(const bf16x8*)&src[0];
        bf16x8 v1 = *(const bf16x8*)&src[8];
#pragma unroll
        for (int i = 0; i < 8; ++i) {
            tile[rr * 65 + cs + i]     = v0[i];
            tile[rr * 65 + cs + 8 + i] = v1[i];
        }
        __syncthreads();
        bf16x8 o0, o1;
#pragma unroll
        for (int i = 0; i < 8; ++i) {
            o0[i] = tile[(cs + i) * 65 + rr];
            o1[i] = tile[(cs + 8 + i) * 65 + rr];
        }
        bf16_t* dst = Vt + (size_t)seg * 262144 + (size_t)(eb * 64 + rr) * 256 + kb * 64 + cs;
        *(bf16x8*)&dst[0] = o0;
        *(bf16x8*)&dst[8] = o1;
    }
}

// ---------- LayerNorm (in place, bf16x8, 2 rows per block) ----------
__global__ __launch_bounds__(256)
void ln_kernel(bf16_t* __restrict__ qkv,
               const float* __restrict__ gamma, const float* __restrict__ beta)
{
    const int t = threadIdx.x;
    const int r = t >> 7;                       // 0/1: row within pair
    const int row = blockIdx.x * 2 + r;
    const int which = blockIdx.y;               // 0=q 1=k 2=v
    bf16_t* p = qkv + (size_t)row * 3072 + which * 1024;
    const int li = t & 127;
    const int c0 = li * 8;

    bf16x8 v = *(const bf16x8*)&p[c0];
    float f[8];
    float s = 0.f, ss = 0.f;
#pragma unroll
    for (int i = 0; i < 8; ++i) { f[i] = (float)v[i]; s += f[i]; ss += f[i] * f[i]; }
#pragma unroll
    for (int o = 32; o; o >>= 1) { s += __shfl_xor(s, o); ss += __shfl_xor(ss, o); }

    __shared__ float rs_[4], rss_[4];
    const int wave = t >> 6, lane = t & 63;
    if (lane == 0) { rs_[wave] = s; rss_[wave] = ss; }
    __syncthreads();
    s  = rs_[2 * r] + rs_[2 * r + 1];
    ss = rss_[2 * r] + rss_[2 * r + 1];

    const float mu   = s * (1.f / 1024.f);
    const float var  = ss * (1.f / 1024.f) - mu * mu;
    const float rstd = rsqrtf(var + 1e-5f);

    bf16x8 o;
#pragma unroll
    for (int i = 0; i < 8; ++i)
        o[i] = (bf16_t)((f[i] - mu) * rstd * gamma[c0 + i] + beta[c0 + i]);
    *(bf16x8*)&p[c0] = o;
}

// ---------- causal softmax: S[32*256][256] f32 -> P bf16 ----------
__global__ __launch_bounds__(256)
void softmax_kernel(const float* __restrict__ S, bf16_t* __restrict__ P)
{
    const int q = blockIdx.x & 255;
    const size_t base = (size_t)blockIdx.x * 256;
    const int c = threadIdx.x;
    const bool ok = (c <= q);

    float v = ok ? S[base + c] * (1.f / 32.f) : -3.0e38f;
    float m = v;
#pragma unroll
    for (int o = 32; o; o >>= 1) m = fmaxf(m, __shfl_xor(m, o));

    __shared__ float rm[4], rsum[4];
    const int wave = c >> 6, lane = c & 63;
    if (lane == 0) rm[wave] = m;
    __syncthreads();
    m = fmaxf(fmaxf(rm[0], rm[1]), fmaxf(rm[2], rm[3]));

    float e = ok ? __expf(v - m) : 0.f;
    float s = e;
#pragma unroll
    for (int o = 32; o; o >>= 1) s += __shfl_xor(s, o);
    if (lane == 0) rsum[wave] = s;
    __syncthreads();
    s = rsum[0] + rsum[1] + rsum[2] + rsum[3];

    P[base + c] = (bf16_t)(e / s);
}

// ---------- launch ----------

extern "C" void kernel_launch(void* const* d_in, const int* in_sizes, int n_in,
                              void* d_out, int out_size, void* d_ws, size_t ws_size,
                              hipStream_t stream)
{
    const float* x     = (const float*)d_in[0];
    const float* Wq    = (const float*)d_in[1];
    const float* Wk    = (const float*)d_in[2];
    const float* Wv    = (const float*)d_in[3];
    const float* Wo    = (const float*)d_in[4];
    const float* gamma = (const float*)d_in[5];
    const float* beta  = (const float*)d_in[6];
    float* out = (float*)d_out;

    char* ws = (char*)d_ws;
    bf16_t* Xe   = (bf16_t*)(ws);                  // 8192x1024 bf16   (16 MB)
    bf16_t* Wqkv = (bf16_t*)(ws + (16u  << 20));   // 3072x1024 bf16   ( 6 MB)
    bf16_t* Wob  = (bf16_t*)(ws + (22u  << 20));   // 1024x1024 bf16   ( 2 MB)
    bf16_t* QKV  = (bf16_t*)(ws + (24u  << 20));   // 8192x3072 bf16   (48 MB)
    float*  Smat = (float*) (ws + (72u  << 20));   // 32x256x256 f32   ( 8 MB)
    bf16_t* P    = (bf16_t*)(ws + (80u  << 20));   // 32x256x256 bf16  ( 4 MB)
    bf16_t* Vt   = (bf16_t*)(ws + (84u  << 20));   // 32x1024x256 bf16 (16 MB)
    bf16_t* Y    = (bf16_t*)(ws + (100u << 20));   // 8192x1024 bf16   (16 MB)

    // prep: weight casts + dilated gather (one launch)
    prep_kernel<<<12288, 256, 0, stream>>>(Wq, Wk, Wv, Wo, x, Wqkv, Wob, Xe);

    // QKV projection: [8192,1024] x [3072,1024]^T -> [8192,3072] bf16
    // persistent 3 sub-tiles/block, 256 blocks = 1/CU, XCD-chunked
    gemm_mt<0, 3><<<dim3(8, 32), 512, 0, stream>>>(
        Xe, Wqkv, QKV, 1024, 1024, 3072);

    // LayerNorm q,k,v in place
    ln_kernel<<<dim3(4096, 3), 256, 0, stream>>>(QKV, gamma, beta);

    // merged: S = Q K^T (causal-skip) + V transpose
    qk_tr_kernel<<<96 + 2048, 256, 0, stream>>>(QKV, Smat, Vt);

    // causal softmax -> P bf16
    softmax_kernel<<<8192, 256, 0, stream>>>(Smat, P);

    // Y = P V per segment (tri: bm==0 blocks only need K=128)
    gemm_nt<0><<<dim3(8, 2, 32), 256, 0, stream>>>(
        P, Vt, Y, 256, 256, 256, 1024,
        65536L, 262144L, 262144L, 1);

    // out = Y Wo^T scattered to even rows of d_out, odd rows zeroed
    // persistent NSUB=1, 256 blocks, XCD-chunked
    gemm_mt<2, 1><<<dim3(8, 32), 512, 0, stream>>>(
        Y, Wob, out, 1024, 1024, 1024);
}